// Round 1
// baseline (1213.570 us; speedup 1.0000x reference)
//
#include <hip/hip_runtime.h>
#include <hip/hip_bf16.h>

#define BB 16
#define TTc 256
#define SS 2048
#define DD 512
#define II 1024
#define LL 4
#define MAXPOSc 4096

typedef __bf16 bf8_t __attribute__((ext_vector_type(8)));
typedef float  f4_t  __attribute__((ext_vector_type(4)));

// ---------------- weight transpose + cast: (L,R,C) f32 -> (L,C,R) bf16 ----------------
__global__ void transpose_bf16_kernel(const float* __restrict__ in, __bf16* __restrict__ out,
                                      int R, int C)
{
    long idx = (long)blockIdx.x * 256 + threadIdx.x;
    long RC = (long)R * C;
    long total = RC * LL;
    if (idx >= total) return;
    int m = (int)(idx / RC);
    long rem = idx - (long)m * RC;
    int c = (int)(rem / R);
    int r = (int)(rem - (long)c * R);
    out[idx] = (__bf16)in[(long)m * RC + (long)r * C + c];
}

// ---------------- GRN flag: any(grn_g != 0 || grn_b != 0) per layer ----------------
__global__ __launch_bounds__(256) void grn_flag_kernel(const float* __restrict__ gg,
                                                       const float* __restrict__ gb,
                                                       int* __restrict__ flag)
{
    int l = blockIdx.x;
    __shared__ int any_s;
    if (threadIdx.x == 0) any_s = 0;
    __syncthreads();
    int a = 0;
    for (int i = threadIdx.x; i < II; i += 256)
        a |= (gg[l * II + i] != 0.f) | (gb[l * II + i] != 0.f);
    if (a) atomicOr(&any_s, 1);
    __syncthreads();
    if (threadIdx.x == 0) flag[l] = any_s;
}

// ---------------- embedding + rope-add + mask ----------------
__global__ __launch_bounds__(128) void embed_kernel(const int* __restrict__ text,
                                                    const float* __restrict__ table,
                                                    const float* __restrict__ freq,
                                                    float* __restrict__ x,
                                                    float* __restrict__ keepf)
{
    int m = blockIdx.x;
    int b = m >> 11;          // S = 2048
    int t = m & (SS - 1);
    int tp = 0;
    if (t < TTc) tp = text[b * TTc + t] + 1;
    if (threadIdx.x == 0) keepf[m] = (tp != 0) ? 1.f : 0.f;
    int d = threadIdx.x * 4;
    f4_t o = {0.f, 0.f, 0.f, 0.f};
    if (tp != 0) {
        f4_t e = *reinterpret_cast<const f4_t*>(&table[(size_t)tp * DD + d]);
        f4_t f = *reinterpret_cast<const f4_t*>(&freq[(size_t)t * DD + d]);
        o = e + f;
    }
    *reinterpret_cast<f4_t*>(&x[(size_t)m * DD + d]) = o;
}

// ---------------- per-batch counts + valid-position compaction ----------------
__global__ __launch_bounds__(256) void counts_kernel(const float* __restrict__ keepf,
                                                     const int* __restrict__ audio,
                                                     int* __restrict__ counts,
                                                     int* __restrict__ vpos)
{
    int b = blockIdx.x, tid = threadIdx.x;
    int mask8 = 0, cnt = 0;
#pragma unroll
    for (int j = 0; j < 8; ++j) {
        int t = tid * 8 + j;
        int k = keepf[b * SS + t] != 0.f;
        mask8 |= k << j;
        cnt += k;
    }
    __shared__ int sc[256];
    sc[tid] = cnt;
    __syncthreads();
    for (int off = 1; off < 256; off <<= 1) {
        int v = sc[tid];
        int add = (tid >= off) ? sc[tid - off] : 0;
        __syncthreads();
        sc[tid] = v + add;
        __syncthreads();
    }
    int incl = sc[tid];
    int Vn = sc[255];
    int r = incl - cnt;
#pragma unroll
    for (int j = 0; j < 8; ++j)
        if (mask8 & (1 << j)) vpos[b * SS + (r++)] = tid * 8 + j;
    int ac = 0;
#pragma unroll
    for (int j = 0; j < 8; ++j) ac += (audio[b * SS + tid * 8 + j] != 0);
    __syncthreads();
    sc[tid] = ac;
    __syncthreads();
    for (int off = 128; off > 0; off >>= 1) {
        if (tid < off) sc[tid] += sc[tid + off];
        __syncthreads();
    }
    if (tid == 0) { counts[2 * b] = sc[0]; counts[2 * b + 1] = Vn; }
}

// ---------------- depthwise conv(7) + layernorm -> bf16 ----------------
__global__ __launch_bounds__(512) void conv_ln_kernel(const float* __restrict__ x,
                                                      const float* __restrict__ w,
                                                      const float* __restrict__ wb,
                                                      const float* __restrict__ g,
                                                      const float* __restrict__ bta,
                                                      __bf16* __restrict__ hn)
{
    int m = blockIdx.x;
    int t = m & (SS - 1);
    int d = threadIdx.x;
    const float* xr = x + (size_t)m * DD + d;
    float h = wb[d];
#pragma unroll
    for (int k = 0; k < 7; ++k) {
        int t2 = t + k - 3;
        if (t2 >= 0 && t2 < SS) h += xr[(k - 3) * DD] * w[d * 7 + k];
    }
    float s = h, s2 = h * h;
#pragma unroll
    for (int off = 32; off > 0; off >>= 1) {
        s  += __shfl_down(s, off);
        s2 += __shfl_down(s2, off);
    }
    __shared__ float sh1[8], sh2[8];
    __shared__ float mu_s, rstd_s;
    int wv = threadIdx.x >> 6, ln = threadIdx.x & 63;
    if (ln == 0) { sh1[wv] = s; sh2[wv] = s2; }
    __syncthreads();
    if (threadIdx.x == 0) {
        float a = 0.f, bq = 0.f;
#pragma unroll
        for (int i = 0; i < 8; ++i) { a += sh1[i]; bq += sh2[i]; }
        float mu = a / DD;
        float var = bq / DD - mu * mu;
        mu_s = mu;
        rstd_s = rsqrtf(var + 1e-6f);
    }
    __syncthreads();
    float y = (h - mu_s) * rstd_s * g[d] + bta[d];
    hn[(size_t)m * DD + d] = (__bf16)y;
}

// ---------------- bf16 MFMA GEMM: C[M,N] = A[M,K] x Wt[N,K]^T ----------------
// EPI 0: out_bf16 = gelu(acc + bias)       (GEMM1)
// EPI 1: out_f32  = (acc + bias + res) * keep[m]   (GEMM2, in-place residual)
template <int EPI>
__global__ __launch_bounds__(256) void gemm_kernel(const __bf16* __restrict__ A,
                                                   const __bf16* __restrict__ Wt,
                                                   int K, int N,
                                                   const float* __restrict__ bias,
                                                   __bf16* __restrict__ outb,
                                                   float* __restrict__ outf,
                                                   const float* __restrict__ res,
                                                   const float* __restrict__ keep)
{
    __shared__ __bf16 As[128][40];
    __shared__ __bf16 Bs[128][40];
    int tid = threadIdx.x;
    int lane = tid & 63, wid = tid >> 6;
    int n0 = blockIdx.x * 128, m0 = blockIdx.y * 128;
    f4_t acc[4][4];
#pragma unroll
    for (int i = 0; i < 4; ++i)
#pragma unroll
        for (int j = 0; j < 4; ++j) { f4_t z = {0.f, 0.f, 0.f, 0.f}; acc[i][j] = z; }

    int srow = tid >> 2, sq = tid & 3;
    const int wm = (wid >> 1) * 64, wn = (wid & 1) * 64;
    int fr = lane & 15, quad = lane >> 4;

    for (int k0 = 0; k0 < K; k0 += 32) {
#pragma unroll
        for (int it = 0; it < 2; ++it) {
            int r = it * 64 + srow;
            *reinterpret_cast<bf8_t*>(&As[r][sq * 8]) =
                *reinterpret_cast<const bf8_t*>(&A[(size_t)(m0 + r) * K + k0 + sq * 8]);
            *reinterpret_cast<bf8_t*>(&Bs[r][sq * 8]) =
                *reinterpret_cast<const bf8_t*>(&Wt[(size_t)(n0 + r) * K + k0 + sq * 8]);
        }
        __syncthreads();
        bf8_t af[4], bfr[4];
#pragma unroll
        for (int mi = 0; mi < 4; ++mi)
            af[mi] = *reinterpret_cast<const bf8_t*>(&As[wm + mi * 16 + fr][quad * 8]);
#pragma unroll
        for (int ni = 0; ni < 4; ++ni)
            bfr[ni] = *reinterpret_cast<const bf8_t*>(&Bs[wn + ni * 16 + fr][quad * 8]);
#pragma unroll
        for (int mi = 0; mi < 4; ++mi)
#pragma unroll
            for (int ni = 0; ni < 4; ++ni)
                acc[mi][ni] = __builtin_amdgcn_mfma_f32_16x16x32_bf16(af[mi], bfr[ni], acc[mi][ni], 0, 0, 0);
        __syncthreads();
    }

#pragma unroll
    for (int mi = 0; mi < 4; ++mi) {
#pragma unroll
        for (int ni = 0; ni < 4; ++ni) {
            int gn = n0 + wn + ni * 16 + fr;
#pragma unroll
            for (int r = 0; r < 4; ++r) {
                int gm = m0 + wm + mi * 16 + quad * 4 + r;
                float v = acc[mi][ni][r] + bias[gn];
                size_t off = (size_t)gm * N + gn;
                if (EPI == 0) {
                    float gl = 0.5f * v * (1.0f + erff(v * 0.7071067811865475f));
                    outb[off] = (__bf16)gl;
                } else {
                    outf[off] = (v + res[off]) * keep[gm];
                }
            }
        }
    }
}

// ---------------- GRN (general path, gated by flag) ----------------
__global__ void zero_kernel(float* __restrict__ p, int n)
{
    int i = blockIdx.x * 256 + threadIdx.x;
    if (i < n) p[i] = 0.f;
}

__global__ __launch_bounds__(256) void grn_reduce_kernel(const __bf16* __restrict__ hh,
                                                         float* __restrict__ gsum,
                                                         const int* __restrict__ flag, int l)
{
    if (!flag[l]) return;
    int i = blockIdx.x * 256 + threadIdx.x;
    int b = blockIdx.z;
    int s0 = blockIdx.y * (SS / 16);
    float acc = 0.f;
    for (int s = s0; s < s0 + SS / 16; ++s) {
        float v = (float)hh[((size_t)b * SS + s) * II + i];
        acc += v * v;
    }
    atomicAdd(&gsum[b * II + i], acc);
}

__global__ __launch_bounds__(256) void grn_scale_kernel(const float* __restrict__ gsum,
                                                        const float* __restrict__ gg,
                                                        float* __restrict__ scale,
                                                        const int* __restrict__ flag, int l)
{
    if (!flag[l]) return;
    int b = blockIdx.x, tid = threadIdx.x;
    float gx[4];
    float s = 0.f;
#pragma unroll
    for (int j = 0; j < 4; ++j) {
        gx[j] = sqrtf(gsum[b * II + tid + j * 256]);
        s += gx[j];
    }
    __shared__ float red[256];
    red[tid] = s;
    __syncthreads();
    for (int off = 128; off > 0; off >>= 1) {
        if (tid < off) red[tid] += red[tid + off];
        __syncthreads();
    }
    float mean = red[0] / II;
#pragma unroll
    for (int j = 0; j < 4; ++j) {
        int i = tid + j * 256;
        float nx = gx[j] / (mean + 1e-6f);
        scale[b * II + i] = 1.f + gg[l * II + i] * nx;
    }
}

__global__ __launch_bounds__(256) void grn_apply_kernel(__bf16* __restrict__ hh,
                                                        const float* __restrict__ scale,
                                                        const float* __restrict__ gb,
                                                        const int* __restrict__ flag, int l)
{
    if (!flag[l]) return;
    int i = blockIdx.x * 256 + threadIdx.x;
    int b = blockIdx.y;
    float sc_ = scale[b * II + i];
    float off = gb[l * II + i];
    if (!__any(sc_ != 1.f || off != 0.f)) return;
    for (int s = 0; s < SS; ++s) {
        size_t idx = ((size_t)b * SS + s) * II + i;
        hh[idx] = (__bf16)((float)hh[idx] * sc_ + off);
    }
}

// ---------------- final resample / gather ----------------
__global__ __launch_bounds__(128) void gather_kernel(const float* __restrict__ x,
                                                     const int* __restrict__ counts,
                                                     const int* __restrict__ vpos,
                                                     float* __restrict__ out)
{
    int m = blockIdx.x;
    int b = m >> 11;
    int t = m & (SS - 1);
    int A = counts[2 * b], Vn = counts[2 * b + 1];
    int d = threadIdx.x * 4;
    f4_t o = {0.f, 0.f, 0.f, 0.f};
    if (t < A && Vn > 0) {
        int Vs = Vn;
        int base = A / Vs, rem = A % Vs;
        int nb = Vs - rem;
        int split = nb * base;
        int bb = base > 1 ? base : 1;
        int j = (t < split) ? (t / bb) : (nb + (t - split) / (base + 1));
        if (j > Vs - 1) j = Vs - 1;
        int src = vpos[b * SS + j];
        o = *reinterpret_cast<const f4_t*>(&x[((size_t)b * SS + src) * DD + d]);
    }
    *reinterpret_cast<f4_t*>(&out[(size_t)m * DD + d]) = o;
}

// ---------------- launch ----------------
extern "C" void kernel_launch(void* const* d_in, const int* in_sizes, int n_in,
                              void* d_out, int out_size, void* d_ws, size_t ws_size,
                              hipStream_t stream)
{
    const int*   text  = (const int*)d_in[0];
    const int*   audio = (const int*)d_in[1];
    const float* table = (const float*)d_in[3];
    const float* freq  = (const float*)d_in[4];
    const float* dw_w  = (const float*)d_in[5];
    const float* dw_b  = (const float*)d_in[6];
    const float* ln_g  = (const float*)d_in[7];
    const float* ln_b  = (const float*)d_in[8];
    const float* w1    = (const float*)d_in[9];
    const float* b1    = (const float*)d_in[10];
    const float* grn_g = (const float*)d_in[11];
    const float* grn_b = (const float*)d_in[12];
    const float* w2    = (const float*)d_in[13];
    const float* b2    = (const float*)d_in[14];

    char* ws = (char*)d_ws;
    float*  x      = (float*)(ws + 0);                 // 64 MB
    __bf16* hn     = (__bf16*)(ws + 67108864);         // 32 MB
    __bf16* hh     = (__bf16*)(ws + 100663296);        // 64 MB
    __bf16* wt1    = (__bf16*)(ws + 167772160);        // 4 MB
    __bf16* wt2    = (__bf16*)(ws + 171966464);        // 4 MB
    float*  keepf  = (float*)(ws + 176160768);         // 128 KB
    int*    counts = (int*)(ws + 176291840);           // 128 B
    int*    vpos   = (int*)(ws + 176291968);           // 128 KB
    float*  gsum   = (float*)(ws + 176423040);         // 64 KB
    float*  gscale = (float*)(ws + 176488576);         // 64 KB
    int*    gflag  = (int*)(ws + 176554112);           // 16 B
    float*  out    = (float*)d_out;

    transpose_bf16_kernel<<<(LL * DD * II + 255) / 256, 256, 0, stream>>>(w1, wt1, DD, II);
    transpose_bf16_kernel<<<(LL * DD * II + 255) / 256, 256, 0, stream>>>(w2, wt2, II, DD);
    grn_flag_kernel<<<LL, 256, 0, stream>>>(grn_g, grn_b, gflag);
    embed_kernel<<<BB * SS, 128, 0, stream>>>(text, table, freq, x, keepf);
    counts_kernel<<<BB, 256, 0, stream>>>(keepf, audio, counts, vpos);

    for (int l = 0; l < LL; ++l) {
        conv_ln_kernel<<<BB * SS, 512, 0, stream>>>(x, dw_w + l * DD * 7, dw_b + l * DD,
                                                    ln_g + l * DD, ln_b + l * DD, hn);
        gemm_kernel<0><<<dim3(II / 128, (BB * SS) / 128), 256, 0, stream>>>(
            hn, wt1 + (size_t)l * DD * II, DD, II, b1 + l * II, hh, nullptr, nullptr, nullptr);
        zero_kernel<<<(BB * II + 255) / 256, 256, 0, stream>>>(gsum, BB * II);
        grn_reduce_kernel<<<dim3(II / 256, 16, BB), 256, 0, stream>>>(hh, gsum, gflag, l);
        grn_scale_kernel<<<BB, 256, 0, stream>>>(gsum, grn_g, gscale, gflag, l);
        grn_apply_kernel<<<dim3(II / 256, BB), 256, 0, stream>>>(hh, gscale, grn_b, gflag, l);
        gemm_kernel<1><<<dim3(DD / 128, (BB * SS) / 128), 256, 0, stream>>>(
            hh, wt2 + (size_t)l * II * DD, II, DD, b2 + l * DD, nullptr, x, x, keepf);
    }

    gather_kernel<<<BB * SS, 128, 0, stream>>>(x, counts, vpos, out);
}

// Round 2
// 891.359 us; speedup vs baseline: 1.3615x; 1.3615x over previous
//
#include <hip/hip_runtime.h>
#include <hip/hip_bf16.h>

#define BB 16
#define TTc 256
#define SS 2048
#define DD 512
#define II 1024
#define LL 4
#define MAXPOSc 4096
#define CT 8   // tokens per conv block

typedef __bf16 bf8_t __attribute__((ext_vector_type(8)));
typedef __bf16 bf4_t __attribute__((ext_vector_type(4)));
typedef float  f4_t  __attribute__((ext_vector_type(4)));

__device__ __forceinline__ void async_ld16(const __bf16* g, __bf16* lds)
{
    __builtin_amdgcn_global_load_lds(
        (const __attribute__((address_space(1))) void*)g,
        (__attribute__((address_space(3))) void*)lds,
        16, 0, 0);
}

// ---------------- weight transpose + cast: (L,R,C) f32 -> (L,C,R) bf16 ----------------
__global__ void transpose_bf16_kernel(const float* __restrict__ in, __bf16* __restrict__ out,
                                      int R, int C)
{
    long idx = (long)blockIdx.x * 256 + threadIdx.x;
    long RC = (long)R * C;
    long total = RC * LL;
    if (idx >= total) return;
    int m = (int)(idx / RC);
    long rem = idx - (long)m * RC;
    int c = (int)(rem / R);
    int r = (int)(rem - (long)c * R);
    out[idx] = (__bf16)in[(long)m * RC + (long)r * C + c];
}

// ---------------- GRN flag: any(grn_g != 0 || grn_b != 0) per layer ----------------
__global__ __launch_bounds__(256) void grn_flag_kernel(const float* __restrict__ gg,
                                                       const float* __restrict__ gb,
                                                       int* __restrict__ flag)
{
    int l = blockIdx.x;
    __shared__ int any_s;
    if (threadIdx.x == 0) any_s = 0;
    __syncthreads();
    int a = 0;
    for (int i = threadIdx.x; i < II; i += 256)
        a |= (gg[l * II + i] != 0.f) | (gb[l * II + i] != 0.f);
    if (a) atomicOr(&any_s, 1);
    __syncthreads();
    if (threadIdx.x == 0) flag[l] = any_s;
}

// ---------------- embedding + rope-add + mask ----------------
__global__ __launch_bounds__(128) void embed_kernel(const int* __restrict__ text,
                                                    const float* __restrict__ table,
                                                    const float* __restrict__ freq,
                                                    float* __restrict__ x,
                                                    float* __restrict__ keepf)
{
    int m = blockIdx.x;
    int b = m >> 11;          // S = 2048
    int t = m & (SS - 1);
    int tp = 0;
    if (t < TTc) tp = text[b * TTc + t] + 1;
    if (threadIdx.x == 0) keepf[m] = (tp != 0) ? 1.f : 0.f;
    int d = threadIdx.x * 4;
    f4_t o = {0.f, 0.f, 0.f, 0.f};
    if (tp != 0) {
        f4_t e = *reinterpret_cast<const f4_t*>(&table[(size_t)tp * DD + d]);
        f4_t f = *reinterpret_cast<const f4_t*>(&freq[(size_t)t * DD + d]);
        o = e + f;
    }
    *reinterpret_cast<f4_t*>(&x[(size_t)m * DD + d]) = o;
}

// ---------------- per-batch counts + valid-position compaction ----------------
__global__ __launch_bounds__(256) void counts_kernel(const float* __restrict__ keepf,
                                                     const int* __restrict__ audio,
                                                     int* __restrict__ counts,
                                                     int* __restrict__ vpos)
{
    int b = blockIdx.x, tid = threadIdx.x;
    int mask8 = 0, cnt = 0;
#pragma unroll
    for (int j = 0; j < 8; ++j) {
        int t = tid * 8 + j;
        int k = keepf[b * SS + t] != 0.f;
        mask8 |= k << j;
        cnt += k;
    }
    __shared__ int sc[256];
    sc[tid] = cnt;
    __syncthreads();
    for (int off = 1; off < 256; off <<= 1) {
        int v = sc[tid];
        int add = (tid >= off) ? sc[tid - off] : 0;
        __syncthreads();
        sc[tid] = v + add;
        __syncthreads();
    }
    int incl = sc[tid];
    int Vn = sc[255];
    int r = incl - cnt;
#pragma unroll
    for (int j = 0; j < 8; ++j)
        if (mask8 & (1 << j)) vpos[b * SS + (r++)] = tid * 8 + j;
    int ac = 0;
#pragma unroll
    for (int j = 0; j < 8; ++j) ac += (audio[b * SS + tid * 8 + j] != 0);
    __syncthreads();
    sc[tid] = ac;
    __syncthreads();
    for (int off = 128; off > 0; off >>= 1) {
        if (tid < off) sc[tid] += sc[tid + off];
        __syncthreads();
    }
    if (tid == 0) { counts[2 * b] = sc[0]; counts[2 * b + 1] = Vn; }
}

// ---------------- depthwise conv(7) + layernorm -> bf16 (LDS-tiled, 8 tok/block) ----------------
__global__ __launch_bounds__(256) void conv_ln_kernel(const float* __restrict__ x,
                                                      const float* __restrict__ w,
                                                      const float* __restrict__ wb,
                                                      const float* __restrict__ g,
                                                      const float* __restrict__ bta,
                                                      __bf16* __restrict__ hn)
{
    __shared__ float xs[CT + 6][DD];   // 28 KB
    int blk = blockIdx.x;
    int b = blk >> 8;                  // SS/CT = 256 blocks per batch
    int t0 = (blk & 255) * CT;
    int tid = threadIdx.x;
    const float* xb = x + (size_t)b * SS * DD;
#pragma unroll
    for (int it = 0; it < (CT + 6) * (DD / 4) / 256; ++it) {
        int i = it * 256 + tid;
        int ri = i >> 7;               // DD/4 = 128
        int c4 = i & 127;
        int tr = t0 - 3 + ri;
        f4_t v = {0.f, 0.f, 0.f, 0.f};
        if (tr >= 0 && tr < SS) v = *reinterpret_cast<const f4_t*>(&xb[(size_t)tr * DD + c4 * 4]);
        *reinterpret_cast<f4_t*>(&xs[ri][c4 * 4]) = v;
    }
    __syncthreads();
    int tt = tid >> 5;                 // token within tile 0..7
    int lg = tid & 31;
    float hv[16];
    float s = 0.f, s2 = 0.f;
#pragma unroll
    for (int j = 0; j < 4; ++j) {
        int c = lg * 4 + j * 128;
        float a0 = wb[c], a1 = wb[c + 1], a2 = wb[c + 2], a3 = wb[c + 3];
#pragma unroll
        for (int k = 0; k < 7; ++k) {
            f4_t xv = *reinterpret_cast<const f4_t*>(&xs[tt + k][c]);
            a0 += xv[0] * w[(c + 0) * 7 + k];
            a1 += xv[1] * w[(c + 1) * 7 + k];
            a2 += xv[2] * w[(c + 2) * 7 + k];
            a3 += xv[3] * w[(c + 3) * 7 + k];
        }
        hv[j * 4 + 0] = a0; hv[j * 4 + 1] = a1; hv[j * 4 + 2] = a2; hv[j * 4 + 3] = a3;
        s += a0 + a1 + a2 + a3;
        s2 += a0 * a0 + a1 * a1 + a2 * a2 + a3 * a3;
    }
#pragma unroll
    for (int off = 16; off > 0; off >>= 1) {
        s  += __shfl_down(s, off, 32);
        s2 += __shfl_down(s2, off, 32);
    }
    s  = __shfl(s, 0, 32);
    s2 = __shfl(s2, 0, 32);
    float mu = s / DD;
    float rstd = rsqrtf(s2 / DD - mu * mu + 1e-6f);
    __bf16* hr = hn + ((size_t)b * SS + t0 + tt) * DD;
#pragma unroll
    for (int j = 0; j < 4; ++j) {
        int c = lg * 4 + j * 128;
        bf4_t o;
#pragma unroll
        for (int q = 0; q < 4; ++q)
            o[q] = (__bf16)((hv[j * 4 + q] - mu) * rstd * g[c + q] + bta[c + q]);
        *reinterpret_cast<bf4_t*>(&hr[c]) = o;
    }
}

// ---------------- bf16 MFMA GEMM: C[M,N] = A[M,K] x Wt[N,K]^T ----------------
// m97 structure: global_load_lds width=16 staging into unpadded [128][32] tiles.
// EPI 0: out_bf16 = gelu(acc + bias)                 (GEMM1)
// EPI 1: out_f32  = (acc + bias + res) * keep[m]     (GEMM2, in-place residual)
template <int EPI>
__global__ __launch_bounds__(256) void gemm_kernel(const __bf16* __restrict__ A,
                                                   const __bf16* __restrict__ Wt,
                                                   int K, int N,
                                                   const float* __restrict__ bias,
                                                   __bf16* __restrict__ outb,
                                                   float* __restrict__ outf,
                                                   const float* __restrict__ res,
                                                   const float* __restrict__ keep)
{
    __shared__ __bf16 As[128 * 32];
    __shared__ __bf16 Bs[128 * 32];
    int tid = threadIdx.x;
    int lane = tid & 63, wid = tid >> 6;
    int n0 = blockIdx.x * 128, m0 = blockIdx.y * 128;
    f4_t acc[4][4];
#pragma unroll
    for (int i = 0; i < 4; ++i)
#pragma unroll
        for (int j = 0; j < 4; ++j) { f4_t z = {0.f, 0.f, 0.f, 0.f}; acc[i][j] = z; }

    const int wm = (wid >> 1) * 64, wn = (wid & 1) * 64;
    int fr = lane & 15, quad = lane >> 4;

    // staging addresses: wave wid stages rows [wid*32, wid*32+32) of each tile,
    // two issues of 16 rows; lane i covers row i/4, 16B chunk i%4.
    int srow = wid * 32 + (lane >> 2);
    int scol = (lane & 3) * 8;
    const __bf16* ag = &A[(size_t)(m0 + srow) * K + scol];
    const __bf16* bg = &Wt[(size_t)(n0 + srow) * K + scol];
    __bf16* al0 = &As[(wid * 32) * 32];
    __bf16* al1 = &As[(wid * 32 + 16) * 32];
    __bf16* bl0 = &Bs[(wid * 32) * 32];
    __bf16* bl1 = &Bs[(wid * 32 + 16) * 32];

    for (int k0 = 0; k0 < K; k0 += 32) {
        async_ld16(ag, al0);
        async_ld16(ag + (size_t)16 * K, al1);
        async_ld16(bg, bl0);
        async_ld16(bg + (size_t)16 * K, bl1);
        ag += 32; bg += 32;
        __syncthreads();
        bf8_t af[4], bfr[4];
#pragma unroll
        for (int mi = 0; mi < 4; ++mi)
            af[mi] = *reinterpret_cast<const bf8_t*>(&As[(wm + mi * 16 + fr) * 32 + quad * 8]);
#pragma unroll
        for (int ni = 0; ni < 4; ++ni)
            bfr[ni] = *reinterpret_cast<const bf8_t*>(&Bs[(wn + ni * 16 + fr) * 32 + quad * 8]);
#pragma unroll
        for (int mi = 0; mi < 4; ++mi)
#pragma unroll
            for (int ni = 0; ni < 4; ++ni)
                acc[mi][ni] = __builtin_amdgcn_mfma_f32_16x16x32_bf16(af[mi], bfr[ni], acc[mi][ni], 0, 0, 0);
        __syncthreads();
    }

#pragma unroll
    for (int mi = 0; mi < 4; ++mi) {
#pragma unroll
        for (int ni = 0; ni < 4; ++ni) {
            int gn = n0 + wn + ni * 16 + fr;
#pragma unroll
            for (int r = 0; r < 4; ++r) {
                int gm = m0 + wm + mi * 16 + quad * 4 + r;
                float v = acc[mi][ni][r] + bias[gn];
                size_t off = (size_t)gm * N + gn;
                if (EPI == 0) {
                    float gl = 0.5f * v * (1.0f + erff(v * 0.7071067811865475f));
                    outb[off] = (__bf16)gl;
                } else {
                    outf[off] = (v + res[off]) * keep[gm];
                }
            }
        }
    }
}

// ---------------- GRN (general path, gated by flag) ----------------
__global__ void zero_kernel(float* __restrict__ p, int n)
{
    int i = blockIdx.x * 256 + threadIdx.x;
    if (i < n) p[i] = 0.f;
}

__global__ __launch_bounds__(256) void grn_reduce_kernel(const __bf16* __restrict__ hh,
                                                         float* __restrict__ gsum,
                                                         const int* __restrict__ flag, int l)
{
    if (!flag[l]) return;
    int i = blockIdx.x * 256 + threadIdx.x;
    int b = blockIdx.z;
    int s0 = blockIdx.y * (SS / 16);
    float acc = 0.f;
    for (int s = s0; s < s0 + SS / 16; ++s) {
        float v = (float)hh[((size_t)b * SS + s) * II + i];
        acc += v * v;
    }
    atomicAdd(&gsum[b * II + i], acc);
}

__global__ __launch_bounds__(256) void grn_scale_kernel(const float* __restrict__ gsum,
                                                        const float* __restrict__ gg,
                                                        float* __restrict__ scale,
                                                        const int* __restrict__ flag, int l)
{
    if (!flag[l]) return;
    int b = blockIdx.x, tid = threadIdx.x;
    float gx[4];
    float s = 0.f;
#pragma unroll
    for (int j = 0; j < 4; ++j) {
        gx[j] = sqrtf(gsum[b * II + tid + j * 256]);
        s += gx[j];
    }
    __shared__ float red[256];
    red[tid] = s;
    __syncthreads();
    for (int off = 128; off > 0; off >>= 1) {
        if (tid < off) red[tid] += red[tid + off];
        __syncthreads();
    }
    float mean = red[0] / II;
#pragma unroll
    for (int j = 0; j < 4; ++j) {
        int i = tid + j * 256;
        float nx = gx[j] / (mean + 1e-6f);
        scale[b * II + i] = 1.f + gg[l * II + i] * nx;
    }
}

__global__ __launch_bounds__(256) void grn_apply_kernel(__bf16* __restrict__ hh,
                                                        const float* __restrict__ scale,
                                                        const float* __restrict__ gb,
                                                        const int* __restrict__ flag, int l)
{
    if (!flag[l]) return;
    int i = blockIdx.x * 256 + threadIdx.x;
    int b = blockIdx.y;
    float sc_ = scale[b * II + i];
    float off = gb[l * II + i];
    if (!__any(sc_ != 1.f || off != 0.f)) return;
    for (int s = 0; s < SS; ++s) {
        size_t idx = ((size_t)b * SS + s) * II + i;
        hh[idx] = (__bf16)((float)hh[idx] * sc_ + off);
    }
}

// ---------------- final resample / gather ----------------
__global__ __launch_bounds__(128) void gather_kernel(const float* __restrict__ x,
                                                     const int* __restrict__ counts,
                                                     const int* __restrict__ vpos,
                                                     float* __restrict__ out)
{
    int m = blockIdx.x;
    int b = m >> 11;
    int t = m & (SS - 1);
    int A = counts[2 * b], Vn = counts[2 * b + 1];
    int d = threadIdx.x * 4;
    f4_t o = {0.f, 0.f, 0.f, 0.f};
    if (t < A && Vn > 0) {
        int Vs = Vn;
        int base = A / Vs, rem = A % Vs;
        int nb = Vs - rem;
        int split = nb * base;
        int bb = base > 1 ? base : 1;
        int j = (t < split) ? (t / bb) : (nb + (t - split) / (base + 1));
        if (j > Vs - 1) j = Vs - 1;
        int src = vpos[b * SS + j];
        o = *reinterpret_cast<const f4_t*>(&x[((size_t)b * SS + src) * DD + d]);
    }
    *reinterpret_cast<f4_t*>(&out[(size_t)m * DD + d]) = o;
}

// ---------------- launch ----------------
extern "C" void kernel_launch(void* const* d_in, const int* in_sizes, int n_in,
                              void* d_out, int out_size, void* d_ws, size_t ws_size,
                              hipStream_t stream)
{
    const int*   text  = (const int*)d_in[0];
    const int*   audio = (const int*)d_in[1];
    const float* table = (const float*)d_in[3];
    const float* freq  = (const float*)d_in[4];
    const float* dw_w  = (const float*)d_in[5];
    const float* dw_b  = (const float*)d_in[6];
    const float* ln_g  = (const float*)d_in[7];
    const float* ln_b  = (const float*)d_in[8];
    const float* w1    = (const float*)d_in[9];
    const float* b1    = (const float*)d_in[10];
    const float* grn_g = (const float*)d_in[11];
    const float* grn_b = (const float*)d_in[12];
    const float* w2    = (const float*)d_in[13];
    const float* b2    = (const float*)d_in[14];

    char* ws = (char*)d_ws;
    float*  x      = (float*)(ws + 0);                 // 64 MB
    __bf16* hn     = (__bf16*)(ws + 67108864);         // 32 MB
    __bf16* hh     = (__bf16*)(ws + 100663296);        // 64 MB
    __bf16* wt1    = (__bf16*)(ws + 167772160);        // 4 MB
    __bf16* wt2    = (__bf16*)(ws + 171966464);        // 4 MB
    float*  keepf  = (float*)(ws + 176160768);         // 128 KB
    int*    counts = (int*)(ws + 176291840);           // 128 B
    int*    vpos   = (int*)(ws + 176291968);           // 128 KB
    float*  gsum   = (float*)(ws + 176423040);         // 64 KB
    float*  gscale = (float*)(ws + 176488576);         // 64 KB
    int*    gflag  = (int*)(ws + 176554112);           // 16 B
    float*  out    = (float*)d_out;

    transpose_bf16_kernel<<<(LL * DD * II + 255) / 256, 256, 0, stream>>>(w1, wt1, DD, II);
    transpose_bf16_kernel<<<(LL * DD * II + 255) / 256, 256, 0, stream>>>(w2, wt2, II, DD);
    grn_flag_kernel<<<LL, 256, 0, stream>>>(grn_g, grn_b, gflag);
    embed_kernel<<<BB * SS, 128, 0, stream>>>(text, table, freq, x, keepf);
    counts_kernel<<<BB, 256, 0, stream>>>(keepf, audio, counts, vpos);

    for (int l = 0; l < LL; ++l) {
        conv_ln_kernel<<<BB * (SS / CT), 256, 0, stream>>>(x, dw_w + l * DD * 7, dw_b + l * DD,
                                                           ln_g + l * DD, ln_b + l * DD, hn);
        gemm_kernel<0><<<dim3(II / 128, (BB * SS) / 128), 256, 0, stream>>>(
            hn, wt1 + (size_t)l * DD * II, DD, II, b1 + l * II, hh, nullptr, nullptr, nullptr);
        zero_kernel<<<(BB * II + 255) / 256, 256, 0, stream>>>(gsum, BB * II);
        grn_reduce_kernel<<<dim3(II / 256, 16, BB), 256, 0, stream>>>(hh, gsum, gflag, l);
        grn_scale_kernel<<<BB, 256, 0, stream>>>(gsum, grn_g, gscale, gflag, l);
        grn_apply_kernel<<<dim3(II / 256, BB), 256, 0, stream>>>(hh, gscale, grn_b, gflag, l);
        gemm_kernel<1><<<dim3(DD / 128, (BB * SS) / 128), 256, 0, stream>>>(
            hh, wt2 + (size_t)l * II * DD, II, DD, b2 + l * DD, nullptr, x, x, keepf);
    }

    gather_kernel<<<BB * SS, 128, 0, stream>>>(x, counts, vpos, out);
}

// Round 3
// 788.404 us; speedup vs baseline: 1.5393x; 1.1306x over previous
//
#include <hip/hip_runtime.h>
#include <hip/hip_bf16.h>

#define BB 16
#define TTc 256
#define SS 2048
#define DD 512
#define II 1024
#define LL 4
#define MAXPOSc 4096
#define CT 8   // tokens per conv block

typedef __bf16 bf8_t __attribute__((ext_vector_type(8)));
typedef __bf16 bf4_t __attribute__((ext_vector_type(4)));
typedef float  f4_t  __attribute__((ext_vector_type(4)));

__device__ __forceinline__ void async_ld16(const __bf16* g, __bf16* lds)
{
    __builtin_amdgcn_global_load_lds(
        (const __attribute__((address_space(1))) void*)g,
        (__attribute__((address_space(3))) void*)lds,
        16, 0, 0);
}

// fast erf-based exact-GELU (A&S 7.1.26, |err| < 1.5e-7)
__device__ __forceinline__ float gelu_f(float v)
{
    float x  = v * 0.70710678118654752f;
    float ax = fabsf(x);
    float t  = __builtin_amdgcn_rcpf(1.0f + 0.3275911f * ax);
    float poly = ((((1.061405429f * t - 1.453152027f) * t + 1.421413741f) * t
                   - 0.284496736f) * t + 0.254829592f) * t;
    float e = __expf(-x * x);
    float y = 1.0f - poly * e;
    float erfv = copysignf(y, x);
    return 0.5f * v * (1.0f + erfv);
}

// ---------------- weight transpose + cast: (L,R,C) f32 -> (L,C,R) bf16 ----------------
__global__ void transpose_bf16_kernel(const float* __restrict__ in, __bf16* __restrict__ out,
                                      int R, int C)
{
    long idx = (long)blockIdx.x * 256 + threadIdx.x;
    long RC = (long)R * C;
    long total = RC * LL;
    if (idx >= total) return;
    int m = (int)(idx / RC);
    long rem = idx - (long)m * RC;
    int c = (int)(rem / R);
    int r = (int)(rem - (long)c * R);
    out[idx] = (__bf16)in[(long)m * RC + (long)r * C + c];
}

// ---------------- GRN flag: any(grn_g != 0 || grn_b != 0) per layer ----------------
__global__ __launch_bounds__(256) void grn_flag_kernel(const float* __restrict__ gg,
                                                       const float* __restrict__ gb,
                                                       int* __restrict__ flag)
{
    int l = blockIdx.x;
    __shared__ int any_s;
    if (threadIdx.x == 0) any_s = 0;
    __syncthreads();
    int a = 0;
    for (int i = threadIdx.x; i < II; i += 256)
        a |= (gg[l * II + i] != 0.f) | (gb[l * II + i] != 0.f);
    if (a) atomicOr(&any_s, 1);
    __syncthreads();
    if (threadIdx.x == 0) flag[l] = any_s;
}

// ---------------- embedding + rope-add + mask ----------------
__global__ __launch_bounds__(128) void embed_kernel(const int* __restrict__ text,
                                                    const float* __restrict__ table,
                                                    const float* __restrict__ freq,
                                                    float* __restrict__ x,
                                                    float* __restrict__ keepf)
{
    int m = blockIdx.x;
    int b = m >> 11;          // S = 2048
    int t = m & (SS - 1);
    int tp = 0;
    if (t < TTc) tp = text[b * TTc + t] + 1;
    if (threadIdx.x == 0) keepf[m] = (tp != 0) ? 1.f : 0.f;
    int d = threadIdx.x * 4;
    f4_t o = {0.f, 0.f, 0.f, 0.f};
    if (tp != 0) {
        f4_t e = *reinterpret_cast<const f4_t*>(&table[(size_t)tp * DD + d]);
        f4_t f = *reinterpret_cast<const f4_t*>(&freq[(size_t)t * DD + d]);
        o = e + f;
    }
    *reinterpret_cast<f4_t*>(&x[(size_t)m * DD + d]) = o;
}

// ---------------- per-batch counts + valid-position compaction ----------------
__global__ __launch_bounds__(256) void counts_kernel(const float* __restrict__ keepf,
                                                     const int* __restrict__ audio,
                                                     int* __restrict__ counts,
                                                     int* __restrict__ vpos)
{
    int b = blockIdx.x, tid = threadIdx.x;
    int mask8 = 0, cnt = 0;
#pragma unroll
    for (int j = 0; j < 8; ++j) {
        int t = tid * 8 + j;
        int k = keepf[b * SS + t] != 0.f;
        mask8 |= k << j;
        cnt += k;
    }
    __shared__ int sc[256];
    sc[tid] = cnt;
    __syncthreads();
    for (int off = 1; off < 256; off <<= 1) {
        int v = sc[tid];
        int add = (tid >= off) ? sc[tid - off] : 0;
        __syncthreads();
        sc[tid] = v + add;
        __syncthreads();
    }
    int incl = sc[tid];
    int Vn = sc[255];
    int r = incl - cnt;
#pragma unroll
    for (int j = 0; j < 8; ++j)
        if (mask8 & (1 << j)) vpos[b * SS + (r++)] = tid * 8 + j;
    int ac = 0;
#pragma unroll
    for (int j = 0; j < 8; ++j) ac += (audio[b * SS + tid * 8 + j] != 0);
    __syncthreads();
    sc[tid] = ac;
    __syncthreads();
    for (int off = 128; off > 0; off >>= 1) {
        if (tid < off) sc[tid] += sc[tid + off];
        __syncthreads();
    }
    if (tid == 0) { counts[2 * b] = sc[0]; counts[2 * b + 1] = Vn; }
}

// ---------------- depthwise conv(7) + layernorm -> bf16 (LDS-tiled, 8 tok/block) ----------------
__global__ __launch_bounds__(256) void conv_ln_kernel(const float* __restrict__ x,
                                                      const float* __restrict__ w,
                                                      const float* __restrict__ wb,
                                                      const float* __restrict__ g,
                                                      const float* __restrict__ bta,
                                                      __bf16* __restrict__ hn)
{
    __shared__ float xs[CT + 6][DD];   // 28 KB
    int blk = blockIdx.x;
    int b = blk >> 8;                  // SS/CT = 256 blocks per batch
    int t0 = (blk & 255) * CT;
    int tid = threadIdx.x;
    const float* xb = x + (size_t)b * SS * DD;
#pragma unroll
    for (int it = 0; it < (CT + 6) * (DD / 4) / 256; ++it) {
        int i = it * 256 + tid;
        int ri = i >> 7;               // DD/4 = 128
        int c4 = i & 127;
        int tr = t0 - 3 + ri;
        f4_t v = {0.f, 0.f, 0.f, 0.f};
        if (tr >= 0 && tr < SS) v = *reinterpret_cast<const f4_t*>(&xb[(size_t)tr * DD + c4 * 4]);
        *reinterpret_cast<f4_t*>(&xs[ri][c4 * 4]) = v;
    }
    __syncthreads();
    int tt = tid >> 5;                 // token within tile 0..7
    int lg = tid & 31;
    float hv[16];
    float s = 0.f, s2 = 0.f;
#pragma unroll
    for (int j = 0; j < 4; ++j) {
        int c = lg * 4 + j * 128;
        float a0 = wb[c], a1 = wb[c + 1], a2 = wb[c + 2], a3 = wb[c + 3];
#pragma unroll
        for (int k = 0; k < 7; ++k) {
            f4_t xv = *reinterpret_cast<const f4_t*>(&xs[tt + k][c]);
            a0 += xv[0] * w[(c + 0) * 7 + k];
            a1 += xv[1] * w[(c + 1) * 7 + k];
            a2 += xv[2] * w[(c + 2) * 7 + k];
            a3 += xv[3] * w[(c + 3) * 7 + k];
        }
        hv[j * 4 + 0] = a0; hv[j * 4 + 1] = a1; hv[j * 4 + 2] = a2; hv[j * 4 + 3] = a3;
        s += a0 + a1 + a2 + a3;
        s2 += a0 * a0 + a1 * a1 + a2 * a2 + a3 * a3;
    }
#pragma unroll
    for (int off = 16; off > 0; off >>= 1) {
        s  += __shfl_down(s, off, 32);
        s2 += __shfl_down(s2, off, 32);
    }
    s  = __shfl(s, 0, 32);
    s2 = __shfl(s2, 0, 32);
    float mu = s / DD;
    float rstd = rsqrtf(s2 / DD - mu * mu + 1e-6f);
    __bf16* hr = hn + ((size_t)b * SS + t0 + tt) * DD;
#pragma unroll
    for (int j = 0; j < 4; ++j) {
        int c = lg * 4 + j * 128;
        bf4_t o;
#pragma unroll
        for (int q = 0; q < 4; ++q)
            o[q] = (__bf16)((hv[j * 4 + q] - mu) * rstd * g[c + q] + bta[c + q]);
        *reinterpret_cast<bf4_t*>(&hr[c]) = o;
    }
}

// ---------------- bf16 MFMA GEMM: C[M,N] = A[M,K] x Wt[N,K]^T ----------------
// m97 staging (global_load_lds width=16, unpadded [128][32] tiles) + XCD swizzle
// + LDS-transposed vectorized epilogue.
// EPI 0: out_bf16 = gelu(acc + bias)                 (GEMM1)
// EPI 1: out_f32  = (acc + bias + res) * keep[m]     (GEMM2, in-place residual)
template <int EPI>
__global__ __launch_bounds__(256) void gemm_kernel(const __bf16* __restrict__ A,
                                                   const __bf16* __restrict__ Wt,
                                                   int K, int N, int nlog,
                                                   const float* __restrict__ bias,
                                                   __bf16* __restrict__ outb,
                                                   float* __restrict__ outf,
                                                   const float* __restrict__ res,
                                                   const float* __restrict__ keep)
{
    __shared__ float smem[4224];               // 16.5 KB: As(8K)+Bs(8K) / cs 32x132 f32
    __bf16* As = (__bf16*)smem;
    __bf16* Bs = As + 128 * 32;
    float*  cs = smem;

    int tid = threadIdx.x;
    int lane = tid & 63, wid = tid >> 6;

    // XCD-aware swizzle: consecutive slots within an XCD share the M-tile.
    int idx = blockIdx.x;
    int xcd = idx & 7;
    int s = idx >> 3;
    int n_t = s & ((1 << nlog) - 1);
    int m_t = ((s >> nlog) << 3) | xcd;
    int n0 = n_t * 128, m0 = m_t * 128;

    f4_t acc[4][4];
#pragma unroll
    for (int i = 0; i < 4; ++i)
#pragma unroll
        for (int j = 0; j < 4; ++j) { f4_t z = {0.f, 0.f, 0.f, 0.f}; acc[i][j] = z; }

    const int wm = (wid >> 1) * 64, wn = (wid & 1) * 64;
    int fr = lane & 15, quad = lane >> 4;

    int srow = wid * 32 + (lane >> 2);
    int scol = (lane & 3) * 8;
    const __bf16* ag = &A[(size_t)(m0 + srow) * K + scol];
    const __bf16* bg = &Wt[(size_t)(n0 + srow) * K + scol];
    __bf16* al0 = &As[(wid * 32) * 32];
    __bf16* al1 = &As[(wid * 32 + 16) * 32];
    __bf16* bl0 = &Bs[(wid * 32) * 32];
    __bf16* bl1 = &Bs[(wid * 32 + 16) * 32];

    for (int k0 = 0; k0 < K; k0 += 32) {
        async_ld16(ag, al0);
        async_ld16(ag + (size_t)16 * K, al1);
        async_ld16(bg, bl0);
        async_ld16(bg + (size_t)16 * K, bl1);
        ag += 32; bg += 32;
        __syncthreads();
        bf8_t af[4], bfr[4];
#pragma unroll
        for (int mi = 0; mi < 4; ++mi)
            af[mi] = *reinterpret_cast<const bf8_t*>(&As[(wm + mi * 16 + fr) * 32 + quad * 8]);
#pragma unroll
        for (int ni = 0; ni < 4; ++ni)
            bfr[ni] = *reinterpret_cast<const bf8_t*>(&Bs[(wn + ni * 16 + fr) * 32 + quad * 8]);
#pragma unroll
        for (int mi = 0; mi < 4; ++mi)
#pragma unroll
            for (int ni = 0; ni < 4; ++ni)
                acc[mi][ni] = __builtin_amdgcn_mfma_f32_16x16x32_bf16(af[mi], bfr[ni], acc[mi][ni], 0, 0, 0);
        __syncthreads();
    }

    // ---- epilogue: LDS transpose, 4 chunks of 32 rows x 128 cols ----
    const int lrbase = (wm >> 6) * 16 + quad * 4;
#pragma unroll
    for (int mi = 0; mi < 4; ++mi) {
        __syncthreads();
#pragma unroll
        for (int ni = 0; ni < 4; ++ni) {
            int col = wn + ni * 16 + fr;
#pragma unroll
            for (int r = 0; r < 4; ++r)
                cs[(lrbase + r) * 132 + col] = acc[mi][ni][r];
        }
        __syncthreads();
#pragma unroll
        for (int p = 0; p < 4; ++p) {
            int lr = p * 8 + (tid >> 5);
            int c = (tid & 31) * 4;
            int gr = m0 + ((lr < 16) ? (mi * 16 + lr) : (64 + mi * 16 + (lr - 16)));
            f4_t v = *reinterpret_cast<const f4_t*>(&cs[lr * 132 + c]);
            f4_t bv = *reinterpret_cast<const f4_t*>(&bias[n0 + c]);
            v = v + bv;
            if (EPI == 0) {
                bf4_t o;
#pragma unroll
                for (int q = 0; q < 4; ++q) o[q] = (__bf16)gelu_f(v[q]);
                *reinterpret_cast<bf4_t*>(&outb[(size_t)gr * N + n0 + c]) = o;
            } else {
                f4_t rv = *reinterpret_cast<const f4_t*>(&res[(size_t)gr * N + n0 + c]);
                float kp = keep[gr];
                f4_t o;
#pragma unroll
                for (int q = 0; q < 4; ++q) o[q] = (v[q] + rv[q]) * kp;
                *reinterpret_cast<f4_t*>(&outf[(size_t)gr * N + n0 + c]) = o;
            }
        }
    }
}

// ---------------- GRN (general path, gated by flag) ----------------
__global__ void zero_kernel(float* __restrict__ p, int n)
{
    int i = blockIdx.x * 256 + threadIdx.x;
    if (i < n) p[i] = 0.f;
}

__global__ __launch_bounds__(256) void grn_reduce_kernel(const __bf16* __restrict__ hh,
                                                         float* __restrict__ gsum,
                                                         const int* __restrict__ flag, int l)
{
    if (!flag[l]) return;
    int i = blockIdx.x * 256 + threadIdx.x;
    int b = blockIdx.z;
    int s0 = blockIdx.y * (SS / 16);
    float acc = 0.f;
    for (int s = s0; s < s0 + SS / 16; ++s) {
        float v = (float)hh[((size_t)b * SS + s) * II + i];
        acc += v * v;
    }
    atomicAdd(&gsum[b * II + i], acc);
}

__global__ __launch_bounds__(256) void grn_scale_kernel(const float* __restrict__ gsum,
                                                        const float* __restrict__ gg,
                                                        float* __restrict__ scale,
                                                        const int* __restrict__ flag, int l)
{
    if (!flag[l]) return;
    int b = blockIdx.x, tid = threadIdx.x;
    float gx[4];
    float s = 0.f;
#pragma unroll
    for (int j = 0; j < 4; ++j) {
        gx[j] = sqrtf(gsum[b * II + tid + j * 256]);
        s += gx[j];
    }
    __shared__ float red[256];
    red[tid] = s;
    __syncthreads();
    for (int off = 128; off > 0; off >>= 1) {
        if (tid < off) red[tid] += red[tid + off];
        __syncthreads();
    }
    float mean = red[0] / II;
#pragma unroll
    for (int j = 0; j < 4; ++j) {
        int i = tid + j * 256;
        float nx = gx[j] / (mean + 1e-6f);
        scale[b * II + i] = 1.f + gg[l * II + i] * nx;
    }
}

__global__ __launch_bounds__(256) void grn_apply_kernel(__bf16* __restrict__ hh,
                                                        const float* __restrict__ scale,
                                                        const float* __restrict__ gb,
                                                        const int* __restrict__ flag, int l)
{
    if (!flag[l]) return;
    int i = blockIdx.x * 256 + threadIdx.x;
    int b = blockIdx.y;
    float sc_ = scale[b * II + i];
    float off = gb[l * II + i];
    if (!__any(sc_ != 1.f || off != 0.f)) return;
    for (int s = 0; s < SS; ++s) {
        size_t idx = ((size_t)b * SS + s) * II + i;
        hh[idx] = (__bf16)((float)hh[idx] * sc_ + off);
    }
}

// ---------------- final resample / gather ----------------
__global__ __launch_bounds__(128) void gather_kernel(const float* __restrict__ x,
                                                     const int* __restrict__ counts,
                                                     const int* __restrict__ vpos,
                                                     float* __restrict__ out)
{
    int m = blockIdx.x;
    int b = m >> 11;
    int t = m & (SS - 1);
    int A = counts[2 * b], Vn = counts[2 * b + 1];
    int d = threadIdx.x * 4;
    f4_t o = {0.f, 0.f, 0.f, 0.f};
    if (t < A && Vn > 0) {
        int Vs = Vn;
        int base = A / Vs, rem = A % Vs;
        int nb = Vs - rem;
        int split = nb * base;
        int bb = base > 1 ? base : 1;
        int j = (t < split) ? (t / bb) : (nb + (t - split) / (base + 1));
        if (j > Vs - 1) j = Vs - 1;
        int src = vpos[b * SS + j];
        o = *reinterpret_cast<const f4_t*>(&x[((size_t)b * SS + src) * DD + d]);
    }
    *reinterpret_cast<f4_t*>(&out[(size_t)m * DD + d]) = o;
}

// ---------------- launch ----------------
extern "C" void kernel_launch(void* const* d_in, const int* in_sizes, int n_in,
                              void* d_out, int out_size, void* d_ws, size_t ws_size,
                              hipStream_t stream)
{
    const int*   text  = (const int*)d_in[0];
    const int*   audio = (const int*)d_in[1];
    const float* table = (const float*)d_in[3];
    const float* freq  = (const float*)d_in[4];
    const float* dw_w  = (const float*)d_in[5];
    const float* dw_b  = (const float*)d_in[6];
    const float* ln_g  = (const float*)d_in[7];
    const float* ln_b  = (const float*)d_in[8];
    const float* w1    = (const float*)d_in[9];
    const float* b1    = (const float*)d_in[10];
    const float* grn_g = (const float*)d_in[11];
    const float* grn_b = (const float*)d_in[12];
    const float* w2    = (const float*)d_in[13];
    const float* b2    = (const float*)d_in[14];

    char* ws = (char*)d_ws;
    float*  x      = (float*)(ws + 0);                 // 64 MB
    __bf16* hn     = (__bf16*)(ws + 67108864);         // 32 MB
    __bf16* hh     = (__bf16*)(ws + 100663296);        // 64 MB
    __bf16* wt1    = (__bf16*)(ws + 167772160);        // 4 MB
    __bf16* wt2    = (__bf16*)(ws + 171966464);        // 4 MB
    float*  keepf  = (float*)(ws + 176160768);         // 128 KB
    int*    counts = (int*)(ws + 176291840);           // 128 B
    int*    vpos   = (int*)(ws + 176291968);           // 128 KB
    float*  gsum   = (float*)(ws + 176423040);         // 64 KB
    float*  gscale = (float*)(ws + 176488576);         // 64 KB
    int*    gflag  = (int*)(ws + 176554112);           // 16 B
    float*  out    = (float*)d_out;

    transpose_bf16_kernel<<<(LL * DD * II + 255) / 256, 256, 0, stream>>>(w1, wt1, DD, II);
    transpose_bf16_kernel<<<(LL * DD * II + 255) / 256, 256, 0, stream>>>(w2, wt2, II, DD);
    grn_flag_kernel<<<LL, 256, 0, stream>>>(grn_g, grn_b, gflag);
    embed_kernel<<<BB * SS, 128, 0, stream>>>(text, table, freq, x, keepf);
    counts_kernel<<<BB, 256, 0, stream>>>(keepf, audio, counts, vpos);

    for (int l = 0; l < LL; ++l) {
        conv_ln_kernel<<<BB * (SS / CT), 256, 0, stream>>>(x, dw_w + l * DD * 7, dw_b + l * DD,
                                                           ln_g + l * DD, ln_b + l * DD, hn);
        gemm_kernel<0><<<dim3((II / 128) * 256), 256, 0, stream>>>(
            hn, wt1 + (size_t)l * DD * II, DD, II, 3, b1 + l * II, hh, nullptr, nullptr, nullptr);
        zero_kernel<<<(BB * II + 255) / 256, 256, 0, stream>>>(gsum, BB * II);
        grn_reduce_kernel<<<dim3(II / 256, 16, BB), 256, 0, stream>>>(hh, gsum, gflag, l);
        grn_scale_kernel<<<BB, 256, 0, stream>>>(gsum, grn_g, gscale, gflag, l);
        grn_apply_kernel<<<dim3(II / 256, BB), 256, 0, stream>>>(hh, gscale, grn_b, gflag, l);
        gemm_kernel<1><<<dim3((DD / 128) * 256), 256, 0, stream>>>(
            hh, wt2 + (size_t)l * II * DD, II, DD, 2, b2 + l * DD, nullptr, x, x, keepf);
    }

    gather_kernel<<<BB * SS, 128, 0, stream>>>(x, counts, vpos, out);
}